// Round 2
// baseline (70.962 us; speedup 1.0000x reference)
//
#include <hip/hip_runtime.h>

#if __has_builtin(__builtin_amdgcn_exp2f)
__device__ __forceinline__ float fast_exp2(float x) { return __builtin_amdgcn_exp2f(x); }
#else
__device__ __forceinline__ float fast_exp2(float x) { return exp2f(x); }
#endif

constexpr int C_ = 256;   // centers
constexpr int M_ = 5;     // ensemble size
constexpr float LOG2E = 1.4426950408889634f;

// out[m,n,d] = sum_c exp(-||x_n - c||^2) * sigma^2 * W[m,c,d],  sigma^2 = 1/16
//
// Algebra (unchanged from R1):
//   exp(-d2)/16 = 2^(-L*|x|^2) * 2^(2L*(x.c)) * 2^(-L*|c|^2 - 4),  L = log2(e)
//   w' = w * e^{-|c|^2}/16 folded at staging; per-n scale 2^(-L*|x|^2) at the end.
//
// R2 change: the kernel was LDS-broadcast-bound (3x ds_read_b128 per center
// amortized over only 64 n  ->  1.2M LDS instrs ~ 23 us across 256 CUs, vs
// ~5 us of VALU). Now each lane carries FOUR n values, so each table
// broadcast feeds 256 n: LDS instructions per (n,c) pair drop 4x.
//   block = 256 threads = 4 waves; wave w owns c-chunk [64w, 64w+64);
//   every wave covers the same 256 n (4 per lane); grid = ceil(N/256).
// Cross-chunk combine via 48 KB LDS scratch (reuses the table buffer);
// reduction is ~96 LDS instructions per block -- negligible.
__global__ __launch_bounds__(256, 2) void ensemble_rbf_kernel(
    const float* __restrict__ x,        // [N,2]
    const float* __restrict__ centers,  // [256,2]
    const float* __restrict__ weights,  // [5,256,2]
    float* __restrict__ out,            // [5,N,2]
    int N)
{
    // phase 1: folded table [256][12] = {ux, uy, w'0..w'9} (12 KB used)
    // phase 2: scratch [4 chunks][256 n][12]  (48 KB)
    __shared__ float s_mem[4 * C_ * 12];

    const int tid  = threadIdx.x;
    const int lane = tid & 63;
    const int wv   = tid >> 6;          // c-chunk id

    // ---- stage folded table: thread t fills row t ----
    {
        float2 cv = ((const float2*)centers)[tid];
        float c2  = fmaf(cv.x, cv.x, cv.y * cv.y);
        float s   = fast_exp2(fmaf(c2, -LOG2E, -4.0f));   // e^{-|c|^2} / 16
        float* row = &s_mem[tid * 12];
        row[0] = (2.0f * LOG2E) * cv.x;                   // ux
        row[1] = (2.0f * LOG2E) * cv.y;                   // uy
        const float2* w2 = (const float2*)weights;        // [5][256] float2
        #pragma unroll
        for (int m = 0; m < M_; m++) {
            float2 wvv = w2[m * C_ + tid];                // coalesced
            row[2 + 2 * m]     = wvv.x * s;
            row[2 + 2 * m + 1] = wvv.y * s;
        }
    }
    __syncthreads();

    const int nbase = blockIdx.x * 256;
    const int n0    = nbase + 4 * lane;

    // ---- load 4 n per lane (32B contiguous, fully coalesced) ----
    float2 xv[4];
    if (n0 + 3 < N) {
        const float4* x4 = (const float4*)x;              // 2 n per float4
        float4 a = x4[(nbase >> 1) + 2 * lane];
        float4 b = x4[(nbase >> 1) + 2 * lane + 1];
        xv[0] = make_float2(a.x, a.y);
        xv[1] = make_float2(a.z, a.w);
        xv[2] = make_float2(b.x, b.y);
        xv[3] = make_float2(b.z, b.w);
    } else {
        #pragma unroll
        for (int j = 0; j < 4; j++)
            xv[j] = (n0 + j < N) ? ((const float2*)x)[n0 + j]
                                 : make_float2(0.f, 0.f);
    }

    float acc[4][10];
    #pragma unroll
    for (int j = 0; j < 4; j++)
        #pragma unroll
        for (int k = 0; k < 10; k++) acc[j][k] = 0.f;

    const float4* tab4 = (const float4*)s_mem;
    const int cb3 = wv * 64 * 3;

    #pragma unroll 4
    for (int cc = 0; cc < 64; cc++) {
        float4 t0 = tab4[cb3 + cc * 3 + 0];   // {ux, uy, w'0, w'1}
        float4 t1 = tab4[cb3 + cc * 3 + 1];   // {w'2..w'5}
        float4 t2 = tab4[cb3 + cc * 3 + 2];   // {w'6..w'9}
        const float w[10] = {t0.z, t0.w, t1.x, t1.y, t1.z,
                             t1.w, t2.x, t2.y, t2.z, t2.w};
        #pragma unroll
        for (int j = 0; j < 4; j++) {
            // r = 2^(2L * x.c)
            float r = fast_exp2(fmaf(xv[j].y, t0.y, xv[j].x * t0.x));
            #pragma unroll
            for (int k = 0; k < 10; k++)
                acc[j][k] = fmaf(r, w[k], acc[j][k]);
        }
    }

    // ---- cross-chunk combine via LDS scratch ----
    __syncthreads();   // everyone done reading the table
    #pragma unroll
    for (int j = 0; j < 4; j++) {
        float4* slot = (float4*)&s_mem[(wv * C_ + 4 * lane + j) * 12];
        slot[0] = make_float4(acc[j][0], acc[j][1], acc[j][2], acc[j][3]);
        slot[1] = make_float4(acc[j][4], acc[j][5], acc[j][6], acc[j][7]);
        slot[2] = make_float4(acc[j][8], acc[j][9], 0.f, 0.f);
    }
    __syncthreads();

    const int n = nbase + tid;               // thread t finalizes n_local = t
    if (n < N) {
        float4 s0 = make_float4(0.f, 0.f, 0.f, 0.f);
        float4 s1 = s0, s2 = s0;
        #pragma unroll
        for (int k = 0; k < 4; k++) {
            const float4* slot = (const float4*)&s_mem[(k * C_ + tid) * 12];
            float4 r0 = slot[0], r1 = slot[1], r2 = slot[2];
            s0.x += r0.x; s0.y += r0.y; s0.z += r0.z; s0.w += r0.w;
            s1.x += r1.x; s1.y += r1.y; s1.z += r1.z; s1.w += r1.w;
            s2.x += r2.x; s2.y += r2.y;
        }
        // per-n scale: 2^(-L*|x|^2)
        float2 xn   = ((const float2*)x)[n];              // L1/L2-hot
        float scale = fast_exp2(fmaf(xn.x, xn.x, xn.y * xn.y) * -LOG2E);

        float2* out2 = (float2*)out;
        out2[(size_t)0 * N + n] = make_float2(s0.x * scale, s0.y * scale);
        out2[(size_t)1 * N + n] = make_float2(s0.z * scale, s0.w * scale);
        out2[(size_t)2 * N + n] = make_float2(s1.x * scale, s1.y * scale);
        out2[(size_t)3 * N + n] = make_float2(s1.z * scale, s1.w * scale);
        out2[(size_t)4 * N + n] = make_float2(s2.x * scale, s2.y * scale);
    }
}

extern "C" void kernel_launch(void* const* d_in, const int* in_sizes, int n_in,
                              void* d_out, int out_size, void* d_ws, size_t ws_size,
                              hipStream_t stream) {
    const float* x       = (const float*)d_in[0];  // [N,2]
    const float* centers = (const float*)d_in[1];  // [256,2]
    const float* weights = (const float*)d_in[2];  // [5,256,2]
    float* out = (float*)d_out;                    // [5,N,2]

    int N = in_sizes[0] / 2;
    int grid = (N + 255) / 256;   // 256 n per block
    ensemble_rbf_kernel<<<grid, 256, 0, stream>>>(x, centers, weights, out, N);
}